// Round 10
// baseline (112.621 us; speedup 1.0000x reference)
//
#include <hip/hip_runtime.h>
#include <hip/hip_bf16.h>

// N=2048, D_IN=128, H=256, D_EMB=64
// inputs: 0:x 1:adj(unused) 2:W0 3:b0 4:W1 5:b1 6:W2 7:b2 8:temp 9:theta
// d_out: out[2048*128] then adj_wts[2048*2048]

typedef short bf16x8 __attribute__((ext_vector_type(8)));
typedef float f32x4 __attribute__((ext_vector_type(4)));

__device__ __forceinline__ unsigned short f2bf(float f) {
    unsigned u = __float_as_uint(f);
    unsigned r = u + 0x7fffu + ((u >> 16) & 1u);
    return (unsigned short)(r >> 16);
}

// pack 8 f32 -> bf16x8 with round-half-up
__device__ __forceinline__ bf16x8 pack_rne8(const float* p) {
    union { unsigned u[4]; bf16x8 v; } r;
    #pragma unroll
    for (int i = 0; i < 4; ++i) {
        unsigned lo = __float_as_uint(p[2 * i]) + 0x8000u;
        unsigned hi = __float_as_uint(p[2 * i + 1]) + 0x8000u;
        r.u[i] = __builtin_amdgcn_perm(hi, lo, 0x07060302u);
    }
    return r.v;
}

// truncation-pack (for the already-rounded P tile in k2)
__device__ __forceinline__ bf16x8 pack_bf8(const float* p) {
    union { unsigned u[4]; bf16x8 v; } r;
    #pragma unroll
    for (int i = 0; i < 4; ++i)
        r.u[i] = __builtin_amdgcn_perm(__float_as_uint(p[2 * i + 1]),
                                       __float_as_uint(p[2 * i]), 0x07060302u);
    return r.v;
}

// ---------------- Kernel 1: fused MLP via MFMA, 8 waves ----------------
// grid 128 x 512 thr. Block: 16 rows. GEMM0 split over 8 waves; then waves 0-3
// run GEMM1 while waves 4-7 run GEMM2 concurrently. Phase-2 weight fragments
// prefetched before the barrier.
__global__ __launch_bounds__(512) void k1_mfma(
    const float* __restrict__ x,
    const float* __restrict__ W0, const float* __restrict__ b0,
    const float* __restrict__ W1, const float* __restrict__ b1,
    const float* __restrict__ W2, const float* __restrict__ b2,
    unsigned short* __restrict__ emb_bf,   // [2048][64] bf16
    unsigned short* __restrict__ xlT_bf,   // [128][2048] bf16
    float* __restrict__ sq)                // [2048]
{
    constexpr int LDO = 264;               // out_x LDS stride (bf16 elems)
    __shared__ unsigned short oxb[16 * LDO];
    __shared__ float sqs[4][16];

    const int t = threadIdx.x;
    const int lane = t & 63;
    const int w = t >> 6;      // wave 0..7
    const int m = lane & 15;
    const int q = lane >> 4;
    const int i0 = blockIdx.x * 16;

    // A-fragments of x (rows i0+m, K=128)
    bf16x8 ax[4];
    #pragma unroll
    for (int kb = 0; kb < 4; ++kb) {
        float xf[8];
        *(f32x4*)&xf[0] = *(const f32x4*)(x + (size_t)(i0 + m) * 128 + kb * 32 + q * 8);
        *(f32x4*)&xf[4] = *(const f32x4*)(x + (size_t)(i0 + m) * 128 + kb * 32 + q * 8 + 4);
        ax[kb] = pack_rne8(xf);
    }

    // prefetch phase-2 weight fragments (barrier-independent)
    bf16x8 wp[8];
    float bias2 = 0.f;
    if (w < 4) {
        const int h = w * 16 + m;
        bias2 = b1[h];
        #pragma unroll
        for (int kb = 0; kb < 8; ++kb) {
            float wf[8];
            #pragma unroll
            for (int j = 0; j < 8; ++j) wf[j] = W1[(size_t)(kb * 32 + q * 8 + j) * 64 + h];
            wp[kb] = pack_rne8(wf);
        }
    } else {
        const int w2 = w - 4;
        #pragma unroll
        for (int hh = 0; hh < 2; ++hh) {
            const int c = (w2 * 2 + hh) * 16 + m;
            #pragma unroll
            for (int kb = 0; kb < 4; ++kb) {
                float wf[8];
                #pragma unroll
                for (int j = 0; j < 8; ++j) wf[j] = W2[(size_t)(kb * 32 + q * 8 + j) * 128 + c];
                wp[hh * 4 + kb] = pack_rne8(wf);
            }
        }
    }

    // GEMM0: out_x = relu(x @ W0 + b0), wave w covers cols w*32..w*32+31
    #pragma unroll
    for (int hh = 0; hh < 2; ++hh) {
        const int h = (w * 2 + hh) * 16 + m;
        float bb = b0[h];
        f32x4 acc = {bb, bb, bb, bb};
        #pragma unroll
        for (int kb = 0; kb < 4; ++kb) {
            float wf[8];
            #pragma unroll
            for (int j = 0; j < 8; ++j) wf[j] = W0[(size_t)(kb * 32 + q * 8 + j) * 256 + h];
            acc = __builtin_amdgcn_mfma_f32_16x16x32_bf16(ax[kb], pack_rne8(wf), acc, 0, 0, 0);
        }
        #pragma unroll
        for (int r = 0; r < 4; ++r)
            oxb[(q * 4 + r) * LDO + h] = f2bf(fmaxf(acc[r], 0.0f));
    }
    __syncthreads();

    if (w < 4) {
        // GEMM1 (waves 0-3): emb = relu(out_x @ W1 + b1), cols w*16..w*16+15
        const int h = w * 16 + m;
        f32x4 acc = {bias2, bias2, bias2, bias2};
        #pragma unroll
        for (int kb = 0; kb < 8; ++kb) {
            bf16x8 af = *(const bf16x8*)(&oxb[m * LDO + kb * 32 + q * 8]);
            acc = __builtin_amdgcn_mfma_f32_16x16x32_bf16(af, wp[kb], acc, 0, 0, 0);
        }
        float s2[4];
        #pragma unroll
        for (int r = 0; r < 4; ++r) {
            float e = fmaxf(acc[r], 0.0f);
            emb_bf[(size_t)(i0 + q * 4 + r) * 64 + h] = f2bf(e);
            s2[r] = e * e;
        }
        #pragma unroll
        for (int r = 0; r < 4; ++r) {
            float v = s2[r];
            v += __shfl_xor(v, 1);
            v += __shfl_xor(v, 2);
            v += __shfl_xor(v, 4);
            v += __shfl_xor(v, 8);
            if (m == 0) sqs[w][q * 4 + r] = v;
        }
    } else {
        // GEMM2 (waves 4-7): x_last = x @ W2 + b2, cols (w-4)*32..+31
        const int w2 = w - 4;
        #pragma unroll
        for (int hh = 0; hh < 2; ++hh) {
            const int c = (w2 * 2 + hh) * 16 + m;
            float bb = b2[c];
            f32x4 acc = {bb, bb, bb, bb};
            #pragma unroll
            for (int kb = 0; kb < 4; ++kb)
                acc = __builtin_amdgcn_mfma_f32_16x16x32_bf16(ax[kb], wp[hh * 4 + kb], acc, 0, 0, 0);
            uint2 pk;
            pk.x = (unsigned)f2bf(acc[0]) | ((unsigned)f2bf(acc[1]) << 16);
            pk.y = (unsigned)f2bf(acc[2]) | ((unsigned)f2bf(acc[3]) << 16);
            *(uint2*)(&xlT_bf[(size_t)c * 2048 + i0 + q * 4]) = pk;
        }
    }
    __syncthreads();
    if (t < 16)
        sq[i0 + t] = sqs[0][t] + sqs[1][t] + sqs[2][t] + sqs[3][t];
}

// ---------------- Kernel 2: fused adjacency + A@x_last (partial stores) ----------------
// grid (128 i-tiles, 8 j-strips) x 256 thr. Block: 16 rows x 256 cols in 2 iters.
// ONE barrier per iteration; no atomics, no fences. adjw stored with PLAIN
// coalesced f32x4 stores (NT stores measured ~3x slower end-to-end: R7 vs R9).
__global__ __launch_bounds__(256) void k2f(
    const unsigned short* __restrict__ emb_bf,
    const unsigned short* __restrict__ xlT_bf,
    const float* __restrict__ sq,
    const float* __restrict__ tempp, const float* __restrict__ thetap,
    float* __restrict__ adjw,      // [2048][2048] f32
    float* __restrict__ outPart,   // [8][2048][128]
    float* __restrict__ degPart)   // [8][2048]
{
    constexpr int LDP = 132;
    __shared__ float Pt[2][16 * LDP];
    __shared__ float degS[4][16];

    const int t = threadIdx.x;
    const int lane = t & 63;
    const int w = t >> 6;
    const int m = lane & 15;
    const int q = lane >> 4;
    const int i0 = blockIdx.x * 16;
    const int bj = blockIdx.y;
    const int jstrip0 = bj * 256;
    const float scale = 1.0f + tempp[0];
    const float bias = 5.0f + thetap[0];

    bf16x8 a0 = *(const bf16x8*)(emb_bf + (size_t)(i0 + m) * 64 + q * 8);
    bf16x8 a1 = *(const bf16x8*)(emb_bf + (size_t)(i0 + m) * 64 + 32 + q * 8);
    float sqIr[4];
    #pragma unroll
    for (int r = 0; r < 4; ++r) sqIr[r] = sq[i0 + q * 4 + r];

    f32x4 accO0 = {0.f, 0.f, 0.f, 0.f};
    f32x4 accO1 = {0.f, 0.f, 0.f, 0.f};
    float dega[4] = {0.f, 0.f, 0.f, 0.f};
    const int cg = w * 32;

    #pragma unroll
    for (int jt = 0; jt < 2; ++jt) {
        const int j0 = jstrip0 + jt * 128;
        float* P = &Pt[jt][0];

        // prefetch AX B-fragments (xlT) — independent of the P tile
        bf16x8 xb[8];
        #pragma unroll
        for (int s = 0; s < 4; ++s) {
            const int k = j0 + s * 32 + q * 8;
            xb[2 * s]     = *(const bf16x8*)(xlT_bf + (size_t)(cg + m) * 2048 + k);
            xb[2 * s + 1] = *(const bf16x8*)(xlT_bf + (size_t)(cg + 16 + m) * 2048 + k);
        }

        // S phase: wave w computes cols 32w..32w+31
        #pragma unroll
        for (int s = 0; s < 2; ++s) {
            const int col = (w * 2 + s) * 16 + m;
            const unsigned short* ebj = emb_bf + (size_t)(j0 + col) * 64;
            bf16x8 b0 = *(const bf16x8*)(ebj + q * 8);
            bf16x8 b1 = *(const bf16x8*)(ebj + 32 + q * 8);
            f32x4 S = {0.f, 0.f, 0.f, 0.f};
            S = __builtin_amdgcn_mfma_f32_16x16x32_bf16(a0, b0, S, 0, 0, 0);
            S = __builtin_amdgcn_mfma_f32_16x16x32_bf16(a1, b1, S, 0, 0, 0);

            const float csqJ = sq[j0 + col];
            const int gcol = j0 + col;
            #pragma unroll
            for (int r = 0; r < 4; ++r) {
                int grow = i0 + q * 4 + r;
                float dist = 2.0f * S[r] - sqIr[r] - csqJ;
                float z = scale * dist + bias;
                float p = 1.0f / (1.0f + __expf(-z));
                if (grow == gcol) p += 1.0f;
                dega[r] += p;
                P[(q * 4 + r) * LDP + col] = p;
            }
        }
        __syncthreads();

        // adjw store: coalesced 128B lines, PLAIN stores
        {
            int row = t >> 4;
            int c0 = (t & 15) * 8;
            f32x4 v0 = *(const f32x4*)(&P[row * LDP + c0]);
            f32x4 v1 = *(const f32x4*)(&P[row * LDP + c0 + 4]);
            f32x4* dst = (f32x4*)(adjw + (size_t)(i0 + row) * 2048 + j0 + c0);
            dst[0] = v0;
            dst[1] = v1;
        }

        // AX: acc += P(16x128) @ xlT (prefetched), K=128
        #pragma unroll
        for (int s = 0; s < 4; ++s) {
            float af[8];
            *(f32x4*)(&af[0]) = *(const f32x4*)(&P[m * LDP + s * 32 + q * 8]);
            *(f32x4*)(&af[4]) = *(const f32x4*)(&P[m * LDP + s * 32 + q * 8 + 4]);
            bf16x8 aa = pack_bf8(af);
            accO0 = __builtin_amdgcn_mfma_f32_16x16x32_bf16(aa, xb[2 * s], accO0, 0, 0, 0);
            accO1 = __builtin_amdgcn_mfma_f32_16x16x32_bf16(aa, xb[2 * s + 1], accO1, 0, 0, 0);
        }
    }

    // deg partial: reduce over m-lanes, combine 4 waves via LDS, plain store
    #pragma unroll
    for (int r = 0; r < 4; ++r) {
        float v = dega[r];
        v += __shfl_xor(v, 1);
        v += __shfl_xor(v, 2);
        v += __shfl_xor(v, 4);
        v += __shfl_xor(v, 8);
        if (m == 0) degS[w][q * 4 + r] = v;
    }
    __syncthreads();
    if (t < 16)
        degPart[bj * 2048 + i0 + t] =
            degS[0][t] + degS[1][t] + degS[2][t] + degS[3][t];

    // out partial: plain stores (block owns [bj][i0..i0+15][*])
    float* op = outPart + ((size_t)bj * 2048 + i0) * 128;
    #pragma unroll
    for (int r = 0; r < 4; ++r) {
        op[(q * 4 + r) * 128 + cg + m] = accO0[r];
        op[(q * 4 + r) * 128 + cg + 16 + m] = accO1[r];
    }
}

// ---------------- Kernel 3: out = relu(sum_p outPart / sum_p degPart) ----------------
__global__ __launch_bounds__(256) void k3_fin(
    const float* __restrict__ outPart, const float* __restrict__ degPart,
    float* __restrict__ out)
{
    int idx4 = (blockIdx.x * 256 + threadIdx.x) * 4;
    int row = idx4 >> 7;
    float4 s = make_float4(0.f, 0.f, 0.f, 0.f);
    float d = 0.f;
    #pragma unroll
    for (int p = 0; p < 8; ++p) {
        float4 v = *(const float4*)(&outPart[(size_t)p * 262144 + idx4]);
        s.x += v.x; s.y += v.y; s.z += v.z; s.w += v.w;
        d += degPart[p * 2048 + row];
    }
    float dinv = 1.0f / d;
    s.x = fmaxf(s.x * dinv, 0.f);
    s.y = fmaxf(s.y * dinv, 0.f);
    s.z = fmaxf(s.z * dinv, 0.f);
    s.w = fmaxf(s.w * dinv, 0.f);
    *(float4*)(&out[idx4]) = s;
}

extern "C" void kernel_launch(void* const* d_in, const int* in_sizes, int n_in,
                              void* d_out, int out_size, void* d_ws, size_t ws_size,
                              hipStream_t stream) {
    const float* x     = (const float*)d_in[0];
    const float* W0    = (const float*)d_in[2];
    const float* b0    = (const float*)d_in[3];
    const float* W1    = (const float*)d_in[4];
    const float* b1    = (const float*)d_in[5];
    const float* W2    = (const float*)d_in[6];
    const float* b2    = (const float*)d_in[7];
    const float* temp  = (const float*)d_in[8];
    const float* theta = (const float*)d_in[9];

    char* ws = (char*)d_ws;
    unsigned short* emb_bf = (unsigned short*)(ws);            // 262144 B
    unsigned short* xlT_bf = (unsigned short*)(ws + 262144);   // 524288 B
    float* sq      = (float*)(ws + 786432);                    //   8192 B
    float* degPart = (float*)(ws + 794624);                    //  65536 B
    float* outPart = (float*)(ws + 860160);                    // 8 MiB

    float* out  = (float*)d_out;              // [2048*128]
    float* adjw = (float*)d_out + 262144;     // [2048*2048]

    k1_mfma<<<128, 512, 0, stream>>>(x, W0, b0, W1, b1, W2, b2,
                                     emb_bf, xlT_bf, sq);
    k2f<<<dim3(128, 8), 256, 0, stream>>>(emb_bf, xlT_bf, sq, temp, theta,
                                          adjw, outPart, degPart);
    k3_fin<<<256, 256, 0, stream>>>(outPart, degPart, out);
}

// Round 11
// 110.535 us; speedup vs baseline: 1.0189x; 1.0189x over previous
//
#include <hip/hip_runtime.h>
#include <hip/hip_bf16.h>

// N=2048, D_IN=128, H=256, D_EMB=64
// inputs: 0:x 1:adj(unused) 2:W0 3:b0 4:W1 5:b1 6:W2 7:b2 8:temp 9:theta
// d_out: out[2048*128] then adj_wts[2048*2048]
//
// R11: __launch_bounds__ second arg added (k1: (512,2), k2f: (256,2)) to lift
// the compiler's default VGPR cap — R6 counters showed k2f at VGPR=56 with
// +13MB WRITE / +6MB FETCH vs real I/O = scratch spill round-trip. Also
// sigmoid divide -> v_rcp_f32.

typedef short bf16x8 __attribute__((ext_vector_type(8)));
typedef float f32x4 __attribute__((ext_vector_type(4)));

__device__ __forceinline__ unsigned short f2bf(float f) {
    unsigned u = __float_as_uint(f);
    unsigned r = u + 0x7fffu + ((u >> 16) & 1u);
    return (unsigned short)(r >> 16);
}

// pack 8 f32 -> bf16x8 with round-half-up
__device__ __forceinline__ bf16x8 pack_rne8(const float* p) {
    union { unsigned u[4]; bf16x8 v; } r;
    #pragma unroll
    for (int i = 0; i < 4; ++i) {
        unsigned lo = __float_as_uint(p[2 * i]) + 0x8000u;
        unsigned hi = __float_as_uint(p[2 * i + 1]) + 0x8000u;
        r.u[i] = __builtin_amdgcn_perm(hi, lo, 0x07060302u);
    }
    return r.v;
}

// truncation-pack (for the already-rounded P tile in k2)
__device__ __forceinline__ bf16x8 pack_bf8(const float* p) {
    union { unsigned u[4]; bf16x8 v; } r;
    #pragma unroll
    for (int i = 0; i < 4; ++i)
        r.u[i] = __builtin_amdgcn_perm(__float_as_uint(p[2 * i + 1]),
                                       __float_as_uint(p[2 * i]), 0x07060302u);
    return r.v;
}

// ---------------- Kernel 1: fused MLP via MFMA, 8 waves ----------------
// grid 128 x 512 thr. Block: 16 rows. GEMM0 split over 8 waves; then waves 0-3
// run GEMM1 while waves 4-7 run GEMM2 concurrently.
__global__ __launch_bounds__(512, 2) void k1_mfma(
    const float* __restrict__ x,
    const float* __restrict__ W0, const float* __restrict__ b0,
    const float* __restrict__ W1, const float* __restrict__ b1,
    const float* __restrict__ W2, const float* __restrict__ b2,
    unsigned short* __restrict__ emb_bf,   // [2048][64] bf16
    unsigned short* __restrict__ xlT_bf,   // [128][2048] bf16
    float* __restrict__ sq)                // [2048]
{
    constexpr int LDO = 264;               // out_x LDS stride (bf16 elems)
    __shared__ unsigned short oxb[16 * LDO];
    __shared__ float sqs[4][16];

    const int t = threadIdx.x;
    const int lane = t & 63;
    const int w = t >> 6;      // wave 0..7
    const int m = lane & 15;
    const int q = lane >> 4;
    const int i0 = blockIdx.x * 16;

    // A-fragments of x (rows i0+m, K=128)
    bf16x8 ax[4];
    #pragma unroll
    for (int kb = 0; kb < 4; ++kb) {
        float xf[8];
        *(f32x4*)&xf[0] = *(const f32x4*)(x + (size_t)(i0 + m) * 128 + kb * 32 + q * 8);
        *(f32x4*)&xf[4] = *(const f32x4*)(x + (size_t)(i0 + m) * 128 + kb * 32 + q * 8 + 4);
        ax[kb] = pack_rne8(xf);
    }

    // prefetch phase-2 weight fragments (barrier-independent)
    bf16x8 wp[8];
    float bias2 = 0.f;
    if (w < 4) {
        const int h = w * 16 + m;
        bias2 = b1[h];
        #pragma unroll
        for (int kb = 0; kb < 8; ++kb) {
            float wf[8];
            #pragma unroll
            for (int j = 0; j < 8; ++j) wf[j] = W1[(size_t)(kb * 32 + q * 8 + j) * 64 + h];
            wp[kb] = pack_rne8(wf);
        }
    } else {
        const int w2 = w - 4;
        #pragma unroll
        for (int hh = 0; hh < 2; ++hh) {
            const int c = (w2 * 2 + hh) * 16 + m;
            #pragma unroll
            for (int kb = 0; kb < 4; ++kb) {
                float wf[8];
                #pragma unroll
                for (int j = 0; j < 8; ++j) wf[j] = W2[(size_t)(kb * 32 + q * 8 + j) * 128 + c];
                wp[hh * 4 + kb] = pack_rne8(wf);
            }
        }
    }

    // GEMM0: out_x = relu(x @ W0 + b0), wave w covers cols w*32..w*32+31
    #pragma unroll
    for (int hh = 0; hh < 2; ++hh) {
        const int h = (w * 2 + hh) * 16 + m;
        float bb = b0[h];
        f32x4 acc = {bb, bb, bb, bb};
        #pragma unroll
        for (int kb = 0; kb < 4; ++kb) {
            float wf[8];
            #pragma unroll
            for (int j = 0; j < 8; ++j) wf[j] = W0[(size_t)(kb * 32 + q * 8 + j) * 256 + h];
            acc = __builtin_amdgcn_mfma_f32_16x16x32_bf16(ax[kb], pack_rne8(wf), acc, 0, 0, 0);
        }
        #pragma unroll
        for (int r = 0; r < 4; ++r)
            oxb[(q * 4 + r) * LDO + h] = f2bf(fmaxf(acc[r], 0.0f));
    }
    __syncthreads();

    if (w < 4) {
        // GEMM1 (waves 0-3): emb = relu(out_x @ W1 + b1), cols w*16..w*16+15
        const int h = w * 16 + m;
        f32x4 acc = {bias2, bias2, bias2, bias2};
        #pragma unroll
        for (int kb = 0; kb < 8; ++kb) {
            bf16x8 af = *(const bf16x8*)(&oxb[m * LDO + kb * 32 + q * 8]);
            acc = __builtin_amdgcn_mfma_f32_16x16x32_bf16(af, wp[kb], acc, 0, 0, 0);
        }
        float s2[4];
        #pragma unroll
        for (int r = 0; r < 4; ++r) {
            float e = fmaxf(acc[r], 0.0f);
            emb_bf[(size_t)(i0 + q * 4 + r) * 64 + h] = f2bf(e);
            s2[r] = e * e;
        }
        #pragma unroll
        for (int r = 0; r < 4; ++r) {
            float v = s2[r];
            v += __shfl_xor(v, 1);
            v += __shfl_xor(v, 2);
            v += __shfl_xor(v, 4);
            v += __shfl_xor(v, 8);
            if (m == 0) sqs[w][q * 4 + r] = v;
        }
    } else {
        // GEMM2 (waves 4-7): x_last = x @ W2 + b2, cols (w-4)*32..+31
        const int w2 = w - 4;
        #pragma unroll
        for (int hh = 0; hh < 2; ++hh) {
            const int c = (w2 * 2 + hh) * 16 + m;
            float bb = b2[c];
            f32x4 acc = {bb, bb, bb, bb};
            #pragma unroll
            for (int kb = 0; kb < 4; ++kb)
                acc = __builtin_amdgcn_mfma_f32_16x16x32_bf16(ax[kb], wp[hh * 4 + kb], acc, 0, 0, 0);
            uint2 pk;
            pk.x = (unsigned)f2bf(acc[0]) | ((unsigned)f2bf(acc[1]) << 16);
            pk.y = (unsigned)f2bf(acc[2]) | ((unsigned)f2bf(acc[3]) << 16);
            *(uint2*)(&xlT_bf[(size_t)c * 2048 + i0 + q * 4]) = pk;
        }
    }
    __syncthreads();
    if (t < 16)
        sq[i0 + t] = sqs[0][t] + sqs[1][t] + sqs[2][t] + sqs[3][t];
}

// ---------------- Kernel 2: fused adjacency + A@x_last (partial stores) ----------------
// grid (128 i-tiles, 8 j-strips) x 256 thr. Block: 16 rows x 256 cols in 2 iters.
// ONE barrier per iteration; no atomics, no fences.
__global__ __launch_bounds__(256, 2) void k2f(
    const unsigned short* __restrict__ emb_bf,
    const unsigned short* __restrict__ xlT_bf,
    const float* __restrict__ sq,
    const float* __restrict__ tempp, const float* __restrict__ thetap,
    float* __restrict__ adjw,      // [2048][2048] f32
    float* __restrict__ outPart,   // [8][2048][128]
    float* __restrict__ degPart)   // [8][2048]
{
    constexpr int LDP = 132;
    __shared__ float Pt[2][16 * LDP];
    __shared__ float degS[4][16];

    const int t = threadIdx.x;
    const int lane = t & 63;
    const int w = t >> 6;
    const int m = lane & 15;
    const int q = lane >> 4;
    const int i0 = blockIdx.x * 16;
    const int bj = blockIdx.y;
    const int jstrip0 = bj * 256;
    const float scale = 1.0f + tempp[0];
    const float bias = 5.0f + thetap[0];

    bf16x8 a0 = *(const bf16x8*)(emb_bf + (size_t)(i0 + m) * 64 + q * 8);
    bf16x8 a1 = *(const bf16x8*)(emb_bf + (size_t)(i0 + m) * 64 + 32 + q * 8);
    float sqIr[4];
    #pragma unroll
    for (int r = 0; r < 4; ++r) sqIr[r] = sq[i0 + q * 4 + r];

    f32x4 accO0 = {0.f, 0.f, 0.f, 0.f};
    f32x4 accO1 = {0.f, 0.f, 0.f, 0.f};
    float dega[4] = {0.f, 0.f, 0.f, 0.f};
    const int cg = w * 32;

    #pragma unroll
    for (int jt = 0; jt < 2; ++jt) {
        const int j0 = jstrip0 + jt * 128;
        float* P = &Pt[jt][0];

        // prefetch AX B-fragments (xlT) — independent of the P tile
        bf16x8 xb[8];
        #pragma unroll
        for (int s = 0; s < 4; ++s) {
            const int k = j0 + s * 32 + q * 8;
            xb[2 * s]     = *(const bf16x8*)(xlT_bf + (size_t)(cg + m) * 2048 + k);
            xb[2 * s + 1] = *(const bf16x8*)(xlT_bf + (size_t)(cg + 16 + m) * 2048 + k);
        }

        // S phase: wave w computes cols 32w..32w+31
        #pragma unroll
        for (int s = 0; s < 2; ++s) {
            const int col = (w * 2 + s) * 16 + m;
            const unsigned short* ebj = emb_bf + (size_t)(j0 + col) * 64;
            bf16x8 b0 = *(const bf16x8*)(ebj + q * 8);
            bf16x8 b1 = *(const bf16x8*)(ebj + 32 + q * 8);
            f32x4 S = {0.f, 0.f, 0.f, 0.f};
            S = __builtin_amdgcn_mfma_f32_16x16x32_bf16(a0, b0, S, 0, 0, 0);
            S = __builtin_amdgcn_mfma_f32_16x16x32_bf16(a1, b1, S, 0, 0, 0);

            const float csqJ = sq[j0 + col];
            const int gcol = j0 + col;
            #pragma unroll
            for (int r = 0; r < 4; ++r) {
                int grow = i0 + q * 4 + r;
                float dist = 2.0f * S[r] - sqIr[r] - csqJ;
                float z = scale * dist + bias;
                float p = __builtin_amdgcn_rcpf(1.0f + __expf(-z));
                if (grow == gcol) p += 1.0f;
                dega[r] += p;
                P[(q * 4 + r) * LDP + col] = p;
            }
        }
        __syncthreads();

        // adjw store: coalesced 128B lines, plain stores
        {
            int row = t >> 4;
            int c0 = (t & 15) * 8;
            f32x4 v0 = *(const f32x4*)(&P[row * LDP + c0]);
            f32x4 v1 = *(const f32x4*)(&P[row * LDP + c0 + 4]);
            f32x4* dst = (f32x4*)(adjw + (size_t)(i0 + row) * 2048 + j0 + c0);
            dst[0] = v0;
            dst[1] = v1;
        }

        // AX: acc += P(16x128) @ xlT (prefetched), K=128
        #pragma unroll
        for (int s = 0; s < 4; ++s) {
            float af[8];
            *(f32x4*)(&af[0]) = *(const f32x4*)(&P[m * LDP + s * 32 + q * 8]);
            *(f32x4*)(&af[4]) = *(const f32x4*)(&P[m * LDP + s * 32 + q * 8 + 4]);
            bf16x8 aa = pack_bf8(af);
            accO0 = __builtin_amdgcn_mfma_f32_16x16x32_bf16(aa, xb[2 * s], accO0, 0, 0, 0);
            accO1 = __builtin_amdgcn_mfma_f32_16x16x32_bf16(aa, xb[2 * s + 1], accO1, 0, 0, 0);
        }
    }

    // deg partial: reduce over m-lanes, combine 4 waves via LDS, plain store
    #pragma unroll
    for (int r = 0; r < 4; ++r) {
        float v = dega[r];
        v += __shfl_xor(v, 1);
        v += __shfl_xor(v, 2);
        v += __shfl_xor(v, 4);
        v += __shfl_xor(v, 8);
        if (m == 0) degS[w][q * 4 + r] = v;
    }
    __syncthreads();
    if (t < 16)
        degPart[bj * 2048 + i0 + t] =
            degS[0][t] + degS[1][t] + degS[2][t] + degS[3][t];

    // out partial: plain stores (block owns [bj][i0..i0+15][*])
    float* op = outPart + ((size_t)bj * 2048 + i0) * 128;
    #pragma unroll
    for (int r = 0; r < 4; ++r) {
        op[(q * 4 + r) * 128 + cg + m] = accO0[r];
        op[(q * 4 + r) * 128 + cg + 16 + m] = accO1[r];
    }
}

// ---------------- Kernel 3: out = relu(sum_p outPart / sum_p degPart) ----------------
__global__ __launch_bounds__(256) void k3_fin(
    const float* __restrict__ outPart, const float* __restrict__ degPart,
    float* __restrict__ out)
{
    int idx4 = (blockIdx.x * 256 + threadIdx.x) * 4;
    int row = idx4 >> 7;
    float4 s = make_float4(0.f, 0.f, 0.f, 0.f);
    float d = 0.f;
    #pragma unroll
    for (int p = 0; p < 8; ++p) {
        float4 v = *(const float4*)(&outPart[(size_t)p * 262144 + idx4]);
        s.x += v.x; s.y += v.y; s.z += v.z; s.w += v.w;
        d += degPart[p * 2048 + row];
    }
    float dinv = 1.0f / d;
    s.x = fmaxf(s.x * dinv, 0.f);
    s.y = fmaxf(s.y * dinv, 0.f);
    s.z = fmaxf(s.z * dinv, 0.f);
    s.w = fmaxf(s.w * dinv, 0.f);
    *(float4*)(&out[idx4]) = s;
}

extern "C" void kernel_launch(void* const* d_in, const int* in_sizes, int n_in,
                              void* d_out, int out_size, void* d_ws, size_t ws_size,
                              hipStream_t stream) {
    const float* x     = (const float*)d_in[0];
    const float* W0    = (const float*)d_in[2];
    const float* b0    = (const float*)d_in[3];
    const float* W1    = (const float*)d_in[4];
    const float* b1    = (const float*)d_in[5];
    const float* W2    = (const float*)d_in[6];
    const float* b2    = (const float*)d_in[7];
    const float* temp  = (const float*)d_in[8];
    const float* theta = (const float*)d_in[9];

    char* ws = (char*)d_ws;
    unsigned short* emb_bf = (unsigned short*)(ws);            // 262144 B
    unsigned short* xlT_bf = (unsigned short*)(ws + 262144);   // 524288 B
    float* sq      = (float*)(ws + 786432);                    //   8192 B
    float* degPart = (float*)(ws + 794624);                    //  65536 B
    float* outPart = (float*)(ws + 860160);                    // 8 MiB

    float* out  = (float*)d_out;              // [2048*128]
    float* adjw = (float*)d_out + 262144;     // [2048*2048]

    k1_mfma<<<128, 512, 0, stream>>>(x, W0, b0, W1, b1, W2, b2,
                                     emb_bf, xlT_bf, sq);
    k2f<<<dim3(128, 8), 256, 0, stream>>>(emb_bf, xlT_bf, sq, temp, theta,
                                          adjw, outPart, degPart);
    k3_fin<<<256, 256, 0, stream>>>(outPart, degPart, out);
}

// Round 12
// 109.161 us; speedup vs baseline: 1.0317x; 1.0126x over previous
//
#include <hip/hip_runtime.h>
#include <hip/hip_bf16.h>

// N=2048, D_IN=128, H=256, D_EMB=64
// inputs: 0:x 1:adj(unused) 2:W0 3:b0 4:W1 5:b1 6:W2 7:b2 8:temp 9:theta
// d_out: out[2048*128] then adj_wts[2048*2048]
//
// R12: all bulk stores restructured to cover FULL 128B lines per instruction
// (R6 k2f counters: +12MB WRITE, +6MB FETCH vs real I/O = partial-line RMW).
// adjw: 32-lane x 16B contiguous rows; outPart: float2-packed full lines.

typedef short bf16x8 __attribute__((ext_vector_type(8)));
typedef float f32x4 __attribute__((ext_vector_type(4)));

__device__ __forceinline__ unsigned short f2bf(float f) {
    unsigned u = __float_as_uint(f);
    unsigned r = u + 0x7fffu + ((u >> 16) & 1u);
    return (unsigned short)(r >> 16);
}

// pack 8 f32 -> bf16x8 with round-half-up
__device__ __forceinline__ bf16x8 pack_rne8(const float* p) {
    union { unsigned u[4]; bf16x8 v; } r;
    #pragma unroll
    for (int i = 0; i < 4; ++i) {
        unsigned lo = __float_as_uint(p[2 * i]) + 0x8000u;
        unsigned hi = __float_as_uint(p[2 * i + 1]) + 0x8000u;
        r.u[i] = __builtin_amdgcn_perm(hi, lo, 0x07060302u);
    }
    return r.v;
}

// truncation-pack (for the already-rounded P tile in k2)
__device__ __forceinline__ bf16x8 pack_bf8(const float* p) {
    union { unsigned u[4]; bf16x8 v; } r;
    #pragma unroll
    for (int i = 0; i < 4; ++i)
        r.u[i] = __builtin_amdgcn_perm(__float_as_uint(p[2 * i + 1]),
                                       __float_as_uint(p[2 * i]), 0x07060302u);
    return r.v;
}

// ---------------- Kernel 1: fused MLP via MFMA, 8 waves ----------------
// grid 128 x 512 thr. Block: 16 rows. GEMM0 split over 8 waves; then waves 0-3
// run GEMM1 while waves 4-7 run GEMM2 concurrently.
__global__ __launch_bounds__(512, 2) void k1_mfma(
    const float* __restrict__ x,
    const float* __restrict__ W0, const float* __restrict__ b0,
    const float* __restrict__ W1, const float* __restrict__ b1,
    const float* __restrict__ W2, const float* __restrict__ b2,
    unsigned short* __restrict__ emb_bf,   // [2048][64] bf16
    unsigned short* __restrict__ xlT_bf,   // [128][2048] bf16
    float* __restrict__ sq)                // [2048]
{
    constexpr int LDO = 264;               // out_x LDS stride (bf16 elems)
    __shared__ unsigned short oxb[16 * LDO];
    __shared__ float sqs[4][16];

    const int t = threadIdx.x;
    const int lane = t & 63;
    const int w = t >> 6;      // wave 0..7
    const int m = lane & 15;
    const int q = lane >> 4;
    const int i0 = blockIdx.x * 16;

    // A-fragments of x (rows i0+m, K=128)
    bf16x8 ax[4];
    #pragma unroll
    for (int kb = 0; kb < 4; ++kb) {
        float xf[8];
        *(f32x4*)&xf[0] = *(const f32x4*)(x + (size_t)(i0 + m) * 128 + kb * 32 + q * 8);
        *(f32x4*)&xf[4] = *(const f32x4*)(x + (size_t)(i0 + m) * 128 + kb * 32 + q * 8 + 4);
        ax[kb] = pack_rne8(xf);
    }

    // prefetch phase-2 weight fragments (barrier-independent)
    bf16x8 wp[8];
    float bias2 = 0.f;
    if (w < 4) {
        const int h = w * 16 + m;
        bias2 = b1[h];
        #pragma unroll
        for (int kb = 0; kb < 8; ++kb) {
            float wf[8];
            #pragma unroll
            for (int j = 0; j < 8; ++j) wf[j] = W1[(size_t)(kb * 32 + q * 8 + j) * 64 + h];
            wp[kb] = pack_rne8(wf);
        }
    } else {
        const int w2 = w - 4;
        #pragma unroll
        for (int hh = 0; hh < 2; ++hh) {
            const int c = (w2 * 2 + hh) * 16 + m;
            #pragma unroll
            for (int kb = 0; kb < 4; ++kb) {
                float wf[8];
                #pragma unroll
                for (int j = 0; j < 8; ++j) wf[j] = W2[(size_t)(kb * 32 + q * 8 + j) * 128 + c];
                wp[hh * 4 + kb] = pack_rne8(wf);
            }
        }
    }

    // GEMM0: out_x = relu(x @ W0 + b0), wave w covers cols w*32..w*32+31
    #pragma unroll
    for (int hh = 0; hh < 2; ++hh) {
        const int h = (w * 2 + hh) * 16 + m;
        float bb = b0[h];
        f32x4 acc = {bb, bb, bb, bb};
        #pragma unroll
        for (int kb = 0; kb < 4; ++kb) {
            float wf[8];
            #pragma unroll
            for (int j = 0; j < 8; ++j) wf[j] = W0[(size_t)(kb * 32 + q * 8 + j) * 256 + h];
            acc = __builtin_amdgcn_mfma_f32_16x16x32_bf16(ax[kb], pack_rne8(wf), acc, 0, 0, 0);
        }
        #pragma unroll
        for (int r = 0; r < 4; ++r)
            oxb[(q * 4 + r) * LDO + h] = f2bf(fmaxf(acc[r], 0.0f));
    }
    __syncthreads();

    if (w < 4) {
        // GEMM1 (waves 0-3): emb = relu(out_x @ W1 + b1), cols w*16..w*16+15
        const int h = w * 16 + m;
        f32x4 acc = {bias2, bias2, bias2, bias2};
        #pragma unroll
        for (int kb = 0; kb < 8; ++kb) {
            bf16x8 af = *(const bf16x8*)(&oxb[m * LDO + kb * 32 + q * 8]);
            acc = __builtin_amdgcn_mfma_f32_16x16x32_bf16(af, wp[kb], acc, 0, 0, 0);
        }
        float s2[4];
        #pragma unroll
        for (int r = 0; r < 4; ++r) {
            float e = fmaxf(acc[r], 0.0f);
            emb_bf[(size_t)(i0 + q * 4 + r) * 64 + h] = f2bf(e);
            s2[r] = e * e;
        }
        #pragma unroll
        for (int r = 0; r < 4; ++r) {
            float v = s2[r];
            v += __shfl_xor(v, 1);
            v += __shfl_xor(v, 2);
            v += __shfl_xor(v, 4);
            v += __shfl_xor(v, 8);
            if (m == 0) sqs[w][q * 4 + r] = v;
        }
    } else {
        // GEMM2 (waves 4-7): x_last = x @ W2 + b2, cols (w-4)*32..+31
        const int w2 = w - 4;
        #pragma unroll
        for (int hh = 0; hh < 2; ++hh) {
            const int c = (w2 * 2 + hh) * 16 + m;
            float bb = b2[c];
            f32x4 acc = {bb, bb, bb, bb};
            #pragma unroll
            for (int kb = 0; kb < 4; ++kb)
                acc = __builtin_amdgcn_mfma_f32_16x16x32_bf16(ax[kb], wp[hh * 4 + kb], acc, 0, 0, 0);
            uint2 pk;
            pk.x = (unsigned)f2bf(acc[0]) | ((unsigned)f2bf(acc[1]) << 16);
            pk.y = (unsigned)f2bf(acc[2]) | ((unsigned)f2bf(acc[3]) << 16);
            *(uint2*)(&xlT_bf[(size_t)c * 2048 + i0 + q * 4]) = pk;
        }
    }
    __syncthreads();
    if (t < 16)
        sq[i0 + t] = sqs[0][t] + sqs[1][t] + sqs[2][t] + sqs[3][t];
}

// ---------------- Kernel 2: fused adjacency + A@x_last (partial stores) ----------------
// grid (128 i-tiles, 8 j-strips) x 256 thr. Block: 16 rows x 256 cols in 2 iters.
// ONE barrier per iteration; no atomics, no fences. All global stores cover
// full 128B lines within a single instruction.
__global__ __launch_bounds__(256, 2) void k2f(
    const unsigned short* __restrict__ emb_bf,
    const unsigned short* __restrict__ xlT_bf,
    const float* __restrict__ sq,
    const float* __restrict__ tempp, const float* __restrict__ thetap,
    float* __restrict__ adjw,      // [2048][2048] f32
    float* __restrict__ outPart,   // [8][128][1024] float2 (layout: see store)
    float* __restrict__ degPart)   // [8][2048]
{
    constexpr int LDP = 132;
    __shared__ float Pt[2][16 * LDP];
    __shared__ float degS[4][16];

    const int t = threadIdx.x;
    const int lane = t & 63;
    const int w = t >> 6;
    const int m = lane & 15;
    const int q = lane >> 4;
    const int i0 = blockIdx.x * 16;
    const int bj = blockIdx.y;
    const int jstrip0 = bj * 256;
    const float scale = 1.0f + tempp[0];
    const float bias = 5.0f + thetap[0];

    bf16x8 a0 = *(const bf16x8*)(emb_bf + (size_t)(i0 + m) * 64 + q * 8);
    bf16x8 a1 = *(const bf16x8*)(emb_bf + (size_t)(i0 + m) * 64 + 32 + q * 8);
    float sqIr[4];
    #pragma unroll
    for (int r = 0; r < 4; ++r) sqIr[r] = sq[i0 + q * 4 + r];

    f32x4 accO0 = {0.f, 0.f, 0.f, 0.f};
    f32x4 accO1 = {0.f, 0.f, 0.f, 0.f};
    float dega[4] = {0.f, 0.f, 0.f, 0.f};
    const int cg = w * 32;

    #pragma unroll
    for (int jt = 0; jt < 2; ++jt) {
        const int j0 = jstrip0 + jt * 128;
        float* P = &Pt[jt][0];

        // prefetch AX B-fragments (xlT) — independent of the P tile
        bf16x8 xb[8];
        #pragma unroll
        for (int s = 0; s < 4; ++s) {
            const int k = j0 + s * 32 + q * 8;
            xb[2 * s]     = *(const bf16x8*)(xlT_bf + (size_t)(cg + m) * 2048 + k);
            xb[2 * s + 1] = *(const bf16x8*)(xlT_bf + (size_t)(cg + 16 + m) * 2048 + k);
        }

        // S phase: wave w computes cols 32w..32w+31
        #pragma unroll
        for (int s = 0; s < 2; ++s) {
            const int col = (w * 2 + s) * 16 + m;
            const unsigned short* ebj = emb_bf + (size_t)(j0 + col) * 64;
            bf16x8 b0 = *(const bf16x8*)(ebj + q * 8);
            bf16x8 b1 = *(const bf16x8*)(ebj + 32 + q * 8);
            f32x4 S = {0.f, 0.f, 0.f, 0.f};
            S = __builtin_amdgcn_mfma_f32_16x16x32_bf16(a0, b0, S, 0, 0, 0);
            S = __builtin_amdgcn_mfma_f32_16x16x32_bf16(a1, b1, S, 0, 0, 0);

            const float csqJ = sq[j0 + col];
            const int gcol = j0 + col;
            #pragma unroll
            for (int r = 0; r < 4; ++r) {
                int grow = i0 + q * 4 + r;
                float dist = 2.0f * S[r] - sqIr[r] - csqJ;
                float z = scale * dist + bias;
                float p = __builtin_amdgcn_rcpf(1.0f + __expf(-z));
                if (grow == gcol) p += 1.0f;
                dega[r] += p;
                P[(q * 4 + r) * LDP + col] = p;
            }
        }
        __syncthreads();

        // adjw store: 32 consecutive lanes x 16B = 512B contiguous per
        // instruction -> 4 FULL 128B lines per instr, no partial-line RMW.
        {
            int row = t >> 5;            // 0..7
            int c0 = (t & 31) * 4;       // f32 col 0..124
            f32x4 v0 = *(const f32x4*)(&P[row * LDP + c0]);
            f32x4 v1 = *(const f32x4*)(&P[(row + 8) * LDP + c0]);
            *(f32x4*)(adjw + (size_t)(i0 + row) * 2048 + j0 + c0) = v0;
            *(f32x4*)(adjw + (size_t)(i0 + row + 8) * 2048 + j0 + c0) = v1;
        }

        // AX: acc += P(16x128) @ xlT (prefetched), K=128
        #pragma unroll
        for (int s = 0; s < 4; ++s) {
            float af[8];
            *(f32x4*)(&af[0]) = *(const f32x4*)(&P[m * LDP + s * 32 + q * 8]);
            *(f32x4*)(&af[4]) = *(const f32x4*)(&P[m * LDP + s * 32 + q * 8 + 4]);
            bf16x8 aa = pack_bf8(af);
            accO0 = __builtin_amdgcn_mfma_f32_16x16x32_bf16(aa, xb[2 * s], accO0, 0, 0, 0);
            accO1 = __builtin_amdgcn_mfma_f32_16x16x32_bf16(aa, xb[2 * s + 1], accO1, 0, 0, 0);
        }
    }

    // deg partial: reduce over m-lanes, combine 4 waves via LDS, plain store
    #pragma unroll
    for (int r = 0; r < 4; ++r) {
        float v = dega[r];
        v += __shfl_xor(v, 1);
        v += __shfl_xor(v, 2);
        v += __shfl_xor(v, 4);
        v += __shfl_xor(v, 8);
        if (m == 0) degS[w][q * 4 + r] = v;
    }
    __syncthreads();
    if (t < 16)
        degPart[bj * 2048 + i0 + t] =
            degS[0][t] + degS[1][t] + degS[2][t] + degS[3][t];

    // out partial: float2-packed so each 16-lane group writes one FULL 128B
    // line per instruction. Layout per (strip, i-tile): [(rit*4+w)*16+m] float2.
    float2* opf2 = (float2*)outPart + ((size_t)bj * 128 + blockIdx.x) * 1024;
    #pragma unroll
    for (int r = 0; r < 4; ++r) {
        float2 pk;
        pk.x = accO0[r];
        pk.y = accO1[r];
        opf2[((q * 4 + r) * 4 + w) * 16 + m] = pk;
    }
}

// ---------------- Kernel 3: out = relu(sum_p outPart / sum_p degPart) ----------------
// thread -> (row i, w, m): two output cols (w*32+m, w*32+16+m). 512 blocks.
__global__ __launch_bounds__(256) void k3_fin(
    const float* __restrict__ outPart, const float* __restrict__ degPart,
    float* __restrict__ out)
{
    int gid = blockIdx.x * 256 + threadIdx.x;  // 131072 = 2048 rows * 64 (w,m)
    int i = gid >> 6;
    int wm = gid & 63;
    int w = wm >> 4, m = wm & 15;
    int tile = i >> 4, rit = i & 15;
    size_t base = (size_t)tile * 2048 + (size_t)((rit * 4 + w) * 16 + m) * 2;
    float s0 = 0.f, s1 = 0.f, d = 0.f;
    #pragma unroll
    for (int p = 0; p < 8; ++p) {
        const float* src = outPart + (size_t)p * 262144 + base;
        s0 += src[0];
        s1 += src[1];
        d += degPart[p * 2048 + i];
    }
    float dinv = 1.0f / d;
    out[(size_t)i * 128 + w * 32 + m] = fmaxf(s0 * dinv, 0.f);
    out[(size_t)i * 128 + w * 32 + 16 + m] = fmaxf(s1 * dinv, 0.f);
}

extern "C" void kernel_launch(void* const* d_in, const int* in_sizes, int n_in,
                              void* d_out, int out_size, void* d_ws, size_t ws_size,
                              hipStream_t stream) {
    const float* x     = (const float*)d_in[0];
    const float* W0    = (const float*)d_in[2];
    const float* b0    = (const float*)d_in[3];
    const float* W1    = (const float*)d_in[4];
    const float* b1    = (const float*)d_in[5];
    const float* W2    = (const float*)d_in[6];
    const float* b2    = (const float*)d_in[7];
    const float* temp  = (const float*)d_in[8];
    const float* theta = (const float*)d_in[9];

    char* ws = (char*)d_ws;
    unsigned short* emb_bf = (unsigned short*)(ws);            // 262144 B
    unsigned short* xlT_bf = (unsigned short*)(ws + 262144);   // 524288 B
    float* sq      = (float*)(ws + 786432);                    //   8192 B
    float* degPart = (float*)(ws + 794624);                    //  65536 B
    float* outPart = (float*)(ws + 860160);                    // 8 MiB

    float* out  = (float*)d_out;              // [2048*128]
    float* adjw = (float*)d_out + 262144;     // [2048*2048]

    k1_mfma<<<128, 512, 0, stream>>>(x, W0, b0, W1, b1, W2, b2,
                                     emb_bf, xlT_bf, sq);
    k2f<<<dim3(128, 8), 256, 0, stream>>>(emb_bf, xlT_bf, sq, temp, theta,
                                          adjw, outPart, degPart);
    k3_fin<<<512, 256, 0, stream>>>(outPart, degPart, out);
}